// Round 4
// baseline (403.833 us; speedup 1.0000x reference)
//
#include <hip/hip_runtime.h>
#include <stdint.h>

#define NROI 2000
#define MPAD 2048
#define KP   12544   // 256*49
#define N1   1024
#define NCLS 81
#define NBOX 324
#define N3   405
#define N3P  448
#define BN_EPS 0.001f
#define KSPLIT 8

typedef __attribute__((ext_vector_type(8))) short bf16x8;
typedef __attribute__((ext_vector_type(4))) float f32x4;

__device__ inline unsigned short f2bf(float f) {
  union { float f; unsigned u; } v; v.f = f;
  unsigned r = v.u + 0x7fffu + ((v.u >> 16) & 1u);
  return (unsigned short)(r >> 16);
}

__device__ inline float bf2f(unsigned short h) {
  union { unsigned u; float f; } v; v.u = (unsigned)h << 16; return v.f;
}

__device__ inline void gld16(const unsigned short* g, unsigned short* l) {
  __builtin_amdgcn_global_load_lds(
      (const __attribute__((address_space(1))) void*)g,
      (__attribute__((address_space(3))) void*)l, 16, 0, 0);
}

__device__ inline unsigned part1by1(unsigned x) {
  x &= 0xFF;
  x = (x | (x << 4)) & 0x0F0F;
  x = (x | (x << 2)) & 0x3333;
  x = (x | (x << 1)) & 0x5555;
  return x;
}

// =================== prep_all: all one-time param prep + ROI sort ==========
// blocks [0,1024): repack conv1_w -> w1p [o][hw*256+c] bf16
// blocks [1024,5120): cvt conv2_w -> bf16
// blocks [5120,5568): pack logits_w+bbox_w -> w3b bf16 (448 rows)
// block 5568: BN folding + bias concat
// block 5569: bitonic sort of ROI keys (level, morton(center)) -> perm[2048]
__global__ __launch_bounds__(256) void prep_all(
    const float* __restrict__ c1w, const float* __restrict__ c2w,
    const float* __restrict__ lw, const float* __restrict__ bw,
    const float* c1b, const float* g1, const float* b1, const float* m1, const float* v1,
    const float* c2b, const float* g2, const float* b2, const float* m2, const float* v2,
    const float* lb, const float* bb, const float* __restrict__ rois,
    unsigned short* __restrict__ w1p, unsigned short* __restrict__ w2b,
    unsigned short* __restrict__ w3b,
    float* s1, float* t1, float* s2, float* t2, float* b3, int* __restrict__ perm) {
  __shared__ unsigned sh_u[KP / 2 + 1];
  int b = blockIdx.x;
  int t = threadIdx.x;
  if (b < 1024) {
    // repack_w1: [o][c][hw] -> [o][hw*256+c]
    unsigned short* s = (unsigned short*)sh_u;
    const float* src = c1w + (size_t)b * KP;
    for (int j = t; j < KP; j += 256) s[j] = f2bf(src[j]);  // s[c*49+hw]
    __syncthreads();
    unsigned short* dst = w1p + (size_t)b * KP;
    for (int j = 0; j < 49; ++j) dst[j * 256 + t] = s[t * 49 + j];
  } else if (b < 5120) {
    int j = (b - 1024) * 256 + t;
    w2b[j] = f2bf(c2w[j]);
  } else if (b < 5568) {
    int row = b - 5120;
    for (int k = t; k < 1024; k += 256) {
      float v = (row < NCLS) ? lw[row * 1024 + k]
                             : (row < N3 ? bw[(row - NCLS) * 1024 + k] : 0.0f);
      w3b[row * 1024 + k] = f2bf(v);
    }
  } else if (b == 5568) {
    for (int i = t; i < 1024; i += 256) {
      float s = g1[i] * rsqrtf(v1[i] + BN_EPS);
      s1[i] = s;
      t1[i] = (c1b[i] - m1[i]) * s + b1[i];
      float ss = g2[i] * rsqrtf(v2[i] + BN_EPS);
      s2[i] = ss;
      t2[i] = (c2b[i] - m2[i]) * ss + b2[i];
    }
    for (int i = t; i < N3P; i += 256)
      b3[i] = (i < NCLS) ? lb[i] : (i < N3 ? bb[i - NCLS] : 0.0f);
  } else {
    // bitonic sort 2048 keys: key = (lvl-2)<<27 | morton<<11 | idx
    unsigned* keys = sh_u;
    for (int i = t; i < 2048; i += 256) {
      unsigned key;
      if (i < NROI) {
        float x1 = rois[4 * i + 0], y1 = rois[4 * i + 1];
        float x2 = rois[4 * i + 2], y2 = rois[4 * i + 3];
        float area = (y2 - y1) * (x2 - x1);
        float lf = rintf(log2f(sqrtf(area) / 224.0f)) + 4.0f;
        lf = fminf(fmaxf(lf, 2.0f), 5.0f);
        int lvl = (int)lf;
        float cy = (y1 + y2) * 0.5f * (1.0f / 1024.0f);
        float cx = (x1 + x2) * 0.5f * (1.0f / 1024.0f);
        int yq = min(255, max(0, (int)(cy * 256.0f)));
        int xq = min(255, max(0, (int)(cx * 256.0f)));
        unsigned mort = (part1by1((unsigned)yq) << 1) | part1by1((unsigned)xq);
        key = ((unsigned)(lvl - 2) << 27) | (mort << 11) | (unsigned)i;
      } else {
        key = 0xFFFFF800u | (unsigned)i;
      }
      keys[i] = key;
    }
    for (int k = 2; k <= 2048; k <<= 1) {
      for (int j = k >> 1; j > 0; j >>= 1) {
        __syncthreads();
        for (int p = t; p < 1024; p += 256) {
          int i = ((p & ~(j - 1)) << 1) | (p & (j - 1));
          int ixj = i | j;
          bool up = (i & k) == 0;
          unsigned a = keys[i], bb2 = keys[ixj];
          if ((a > bb2) == up) { keys[i] = bb2; keys[ixj] = a; }
        }
      }
    }
    __syncthreads();
    for (int i = t; i < 2048; i += 256) perm[i] = (int)(keys[i] & 2047u);
  }
}

// =================== fmap transposes, merged: [256][HW] f32 -> [HW][256] bf16
__global__ __launch_bounds__(256) void transpose_all(
    const float* __restrict__ p2, const float* __restrict__ p3,
    const float* __restrict__ p4, const float* __restrict__ p5,
    unsigned short* __restrict__ f2t, unsigned short* __restrict__ f3t,
    unsigned short* __restrict__ f4t, unsigned short* __restrict__ f5t) {
  __shared__ unsigned short s[64][258];
  int b = blockIdx.x;
  const float* src;
  unsigned short* dst;
  int HW;
  if (b < 1024)      { src = p2; dst = f2t; HW = 65536; }
  else if (b < 1280) { b -= 1024; src = p3; dst = f3t; HW = 16384; }
  else if (b < 1344) { b -= 1280; src = p4; dst = f4t; HW = 4096; }
  else               { b -= 1344; src = p5; dst = f5t; HW = 1024; }
  int p0 = b * 64;
  int t = threadIdx.x;
  int px = t & 63;
  int cq = t >> 6;
  for (int c = cq; c < 256; c += 4)
    s[px][c] = f2bf(src[(size_t)c * HW + p0 + px]);
  __syncthreads();
  for (int p = 0; p < 64; ++p)
    dst[(size_t)(p0 + p) * 256 + t] = s[p][t];
}

// =================== ROI Align (sorted order): pooled[b] = roi perm[b] ======
__global__ void roi_align2(const unsigned short* __restrict__ f2t,
                           const unsigned short* __restrict__ f3t,
                           const unsigned short* __restrict__ f4t,
                           const unsigned short* __restrict__ f5t,
                           const float* __restrict__ rois,
                           const int* __restrict__ perm,
                           unsigned short* __restrict__ pooled) {
  int b = blockIdx.x;
  int c = threadIdx.x;  // 0..255 == channel
  int n = perm[b];
  unsigned short* out = pooled + (size_t)b * KP;
  if (n >= NROI) {
    for (int j = 0; j < 49; ++j) out[j * 256 + c] = 0;
    return;
  }
  float x1 = rois[n * 4 + 0], y1 = rois[n * 4 + 1];
  float x2 = rois[n * 4 + 2], y2 = rois[n * 4 + 3];
  float area = (y2 - y1) * (x2 - x1);
  float lvl_f = rintf(log2f(sqrtf(area) / 224.0f)) + 4.0f;
  lvl_f = fminf(fmaxf(lvl_f, 2.0f), 5.0f);
  int lvl = (int)lvl_f;
  const unsigned short* f;
  int H;
  if (lvl == 2)      { f = f2t; H = 256; }
  else if (lvl == 3) { f = f3t; H = 128; }
  else if (lvl == 4) { f = f4t; H = 64;  }
  else               { f = f5t; H = 32;  }
  int W = H;
  const float inv = 1.0f / 1024.0f;
  float yn1 = y1 * inv, xn1 = x1 * inv, yn2 = y2 * inv, xn2 = x2 * inv;
  float hs = (yn2 - yn1) * (H - 1);
  float ws = (xn2 - xn1) * (W - 1);
  float yb = yn1 * (H - 1);
  float xb = xn1 * (W - 1);

  int x0a[7], x1a[7];
  float lxa[7];
#pragma unroll
  for (int px = 0; px < 7; ++px) {
    float xsv = xb + ((float)px / 6.0f) * ws;
    float x0f = floorf(xsv);
    lxa[px] = xsv - x0f;
    int x0 = (int)x0f; x0 = min(max(x0, 0), W - 1);
    x0a[px] = x0;
    x1a[px] = min(x0 + 1, W - 1);
  }
  for (int py = 0; py < 7; ++py) {
    float ysv = yb + ((float)py / 6.0f) * hs;
    float y0f = floorf(ysv);
    float ly = ysv - y0f;
    int y0 = (int)y0f; y0 = min(max(y0, 0), H - 1);
    int y1i = min(y0 + 1, H - 1);
    const unsigned short* r0 = f + ((size_t)y0 * W) * 256 + c;
    const unsigned short* r1 = f + ((size_t)y1i * W) * 256 + c;
#pragma unroll
    for (int px = 0; px < 7; ++px) {
      int x0 = x0a[px] * 256, x1i = x1a[px] * 256;
      float lx = lxa[px];
      float v00 = bf2f(r0[x0]), v01 = bf2f(r0[x1i]);
      float v10 = bf2f(r1[x0]), v11 = bf2f(r1[x1i]);
      float top = v00 + lx * (v01 - v00);
      float bot = v10 + lx * (v11 - v10);
      out[(py * 7 + px) * 256 + c] = f2bf(top + ly * (bot - top));
    }
  }
}

// =================== GEMM1 split-K: 128x128 tile, 4 waves, 4x4 MFMA/wave ===
__global__ __launch_bounds__(256) void gemm1_sk(
    const unsigned short* __restrict__ A, const unsigned short* __restrict__ B,
    float* __restrict__ part) {
  __shared__ unsigned short As[128 * 32];
  __shared__ unsigned short Bs[128 * 32];
  int bm0 = blockIdx.y * 128;
  int bn0 = blockIdx.x * 128;
  int kz = blockIdx.z;
  int t = threadIdx.x;
  int lane = t & 63, w = t >> 6;
  int wm = (w & 1) * 64, wn = (w >> 1) * 64;
  int ln = lane & 15, q = lane >> 4;

  const int KC = KP / KSPLIT;  // 1568 = 49 * 32
  const unsigned short* ga0 = A + (size_t)(bm0 + (t >> 2)) * KP + kz * KC + (t & 3) * 8;
  const unsigned short* ga1 = ga0 + (size_t)64 * KP;
  const unsigned short* gb0 = B + (size_t)(bn0 + (t >> 2)) * KP + kz * KC + (t & 3) * 8;
  const unsigned short* gb1 = gb0 + (size_t)64 * KP;
  unsigned short* la0 = &As[t * 8];
  unsigned short* la1 = &As[t * 8 + 2048];
  unsigned short* lb0 = &Bs[t * 8];
  unsigned short* lb1 = &Bs[t * 8 + 2048];

  f32x4 acc[4][4] = {};

  for (int k0 = 0; k0 < KC; k0 += 32) {
    gld16(ga0 + k0, la0);
    gld16(ga1 + k0, la1);
    gld16(gb0 + k0, lb0);
    gld16(gb1 + k0, lb1);
    __syncthreads();
    bf16x8 af[4], bfr[4];
#pragma unroll
    for (int i = 0; i < 4; ++i) {
      af[i]  = *(const bf16x8*)&As[(wm + i * 16 + ln) * 32 + q * 8];
      bfr[i] = *(const bf16x8*)&Bs[(wn + i * 16 + ln) * 32 + q * 8];
    }
#pragma unroll
    for (int i = 0; i < 4; ++i)
#pragma unroll
      for (int j = 0; j < 4; ++j)
        acc[i][j] = __builtin_amdgcn_mfma_f32_16x16x32_bf16(af[i], bfr[j], acc[i][j], 0, 0, 0);
    __syncthreads();
  }

  float* po = part + (size_t)kz * MPAD * N1;
#pragma unroll
  for (int i = 0; i < 4; ++i)
#pragma unroll
    for (int j = 0; j < 4; ++j)
#pragma unroll
      for (int r = 0; r < 4; ++r) {
        int m = bm0 + wm + i * 16 + q * 4 + r;
        int n = bn0 + wn + j * 16 + ln;
        po[(size_t)m * N1 + n] = acc[i][j][r];
      }
}

// =================== split-K reduce + BN1 + ReLU + un-permute + bf16 =======
// block = one sorted row ms; writes a2 row perm[ms].
__global__ void reduce_sk(const float* __restrict__ part, const int* __restrict__ perm,
                          const float* __restrict__ sc, const float* __restrict__ sh,
                          unsigned short* __restrict__ outb) {
  const size_t P = (size_t)MPAD * N1;
  int ms = blockIdx.x;
  int t = threadIdx.x;  // 0..255, covers 1024 cols as float4
  float4 v = {0.f, 0.f, 0.f, 0.f};
#pragma unroll
  for (int kz = 0; kz < KSPLIT; ++kz) {
    const float4* pk = (const float4*)(part + kz * P + (size_t)ms * N1);
    float4 u = pk[t];
    v.x += u.x; v.y += u.y; v.z += u.z; v.w += u.w;
  }
  int d = perm[ms];
  int n0 = t * 4;
  ushort4 o;
  if (d < NROI) {
    o.x = f2bf(fmaxf(v.x * sc[n0 + 0] + sh[n0 + 0], 0.0f));
    o.y = f2bf(fmaxf(v.y * sc[n0 + 1] + sh[n0 + 1], 0.0f));
    o.z = f2bf(fmaxf(v.z * sc[n0 + 2] + sh[n0 + 2], 0.0f));
    o.w = f2bf(fmaxf(v.w * sc[n0 + 3] + sh[n0 + 3], 0.0f));
  } else {
    o = make_ushort4(0, 0, 0, 0);
  }
  *(ushort4*)(outb + (size_t)d * N1 + n0) = o;
}

// =================== bf16 MFMA GEMM (64x64 tile), B^T input ================
template <int MODE>
__global__ __launch_bounds__(256) void gemm_bt(
    const unsigned short* __restrict__ A, const unsigned short* __restrict__ B,
    int M, int N, int K,
    const float* __restrict__ sc, const float* __restrict__ sh,
    unsigned short* __restrict__ outb, float* __restrict__ outf,
    int validM, int ldo) {
  __shared__ unsigned short As[64 * 32];
  __shared__ unsigned short Bs[64 * 32];
  int bm0 = blockIdx.y * 64;
  int bn0 = blockIdx.x * 64;
  int t = threadIdx.x;
  int lane = t & 63, w = t >> 6;
  int wm = (w & 1) * 32, wn = (w >> 1) * 32;
  int ln = lane & 15, q = lane >> 4;

  const unsigned short* ga = A + (size_t)(bm0 + (t >> 2)) * K + (t & 3) * 8;
  const unsigned short* gb = B + (size_t)(bn0 + (t >> 2)) * K + (t & 3) * 8;
  unsigned short* la = &As[t * 8];
  unsigned short* lb = &Bs[t * 8];

  f32x4 acc00 = {0.f, 0.f, 0.f, 0.f}, acc01 = {0.f, 0.f, 0.f, 0.f};
  f32x4 acc10 = {0.f, 0.f, 0.f, 0.f}, acc11 = {0.f, 0.f, 0.f, 0.f};

  for (int k0 = 0; k0 < K; k0 += 32) {
    gld16(ga + k0, la);
    gld16(gb + k0, lb);
    __syncthreads();
    bf16x8 a0 = *(const bf16x8*)&As[(wm + ln) * 32 + q * 8];
    bf16x8 a1 = *(const bf16x8*)&As[(wm + 16 + ln) * 32 + q * 8];
    bf16x8 b0 = *(const bf16x8*)&Bs[(wn + ln) * 32 + q * 8];
    bf16x8 b1 = *(const bf16x8*)&Bs[(wn + 16 + ln) * 32 + q * 8];
    acc00 = __builtin_amdgcn_mfma_f32_16x16x32_bf16(a0, b0, acc00, 0, 0, 0);
    acc01 = __builtin_amdgcn_mfma_f32_16x16x32_bf16(a0, b1, acc01, 0, 0, 0);
    acc10 = __builtin_amdgcn_mfma_f32_16x16x32_bf16(a1, b0, acc10, 0, 0, 0);
    acc11 = __builtin_amdgcn_mfma_f32_16x16x32_bf16(a1, b1, acc11, 0, 0, 0);
    __syncthreads();
  }

  f32x4 accs[2][2] = {{acc00, acc01}, {acc10, acc11}};
#pragma unroll
  for (int i = 0; i < 2; ++i)
#pragma unroll
    for (int j = 0; j < 2; ++j)
#pragma unroll
      for (int r = 0; r < 4; ++r) {
        int m = bm0 + wm + i * 16 + q * 4 + r;
        int n = bn0 + wn + j * 16 + ln;
        float v = accs[i][j][r];
        if (MODE == 1) {
          float o = fmaxf(v * sc[n] + sh[n], 0.0f);
          outb[(size_t)m * ldo + n] = (m < validM) ? f2bf(o) : (unsigned short)0;
        } else {
          outf[(size_t)m * ldo + n] = v + sh[n];
        }
      }
}

// =================== softmax + output scatter ===============================
__global__ void head(const float* __restrict__ fc3, float* __restrict__ out) {
  int r = blockIdx.x;
  int t = threadIdx.x;  // 0..63
  const float* row = fc3 + (size_t)r * N3P;
  float v0 = (t < NCLS) ? row[t] : -INFINITY;
  float v1 = (t + 64 < NCLS) ? row[t + 64] : -INFINITY;
  float m = fmaxf(v0, v1);
#pragma unroll
  for (int o = 32; o > 0; o >>= 1) m = fmaxf(m, __shfl_xor(m, o, 64));
  float e0 = (t < NCLS) ? expf(v0 - m) : 0.0f;
  float e1 = (t + 64 < NCLS) ? expf(v1 - m) : 0.0f;
  float s = e0 + e1;
#pragma unroll
  for (int o = 32; o > 0; o >>= 1) s += __shfl_xor(s, o, 64);
  float invs = 1.0f / s;
  float* ol = out + (size_t)r * NCLS;
  float* op = out + 162000 + (size_t)r * NCLS;
  float* ob = out + 324000 + (size_t)r * NBOX;
  if (t < NCLS) { ol[t] = v0; op[t] = e0 * invs; }
  if (t + 64 < NCLS) { ol[t + 64] = v1; op[t + 64] = e1 * invs; }
  for (int j = t; j < NBOX; j += 64) ob[j] = row[NCLS + j];
}

extern "C" void kernel_launch(void* const* d_in, const int* in_sizes, int n_in,
                              void* d_out, int out_size, void* d_ws, size_t ws_size,
                              hipStream_t stream) {
  const float* p2  = (const float*)d_in[0];
  const float* p3  = (const float*)d_in[1];
  const float* p4  = (const float*)d_in[2];
  const float* p5  = (const float*)d_in[3];
  const float* roi = (const float*)d_in[4];
  const float* c1w = (const float*)d_in[5];
  const float* c1b = (const float*)d_in[6];
  const float* g1  = (const float*)d_in[7];
  const float* b1  = (const float*)d_in[8];
  const float* m1  = (const float*)d_in[9];
  const float* v1  = (const float*)d_in[10];
  const float* c2w = (const float*)d_in[11];
  const float* c2b = (const float*)d_in[12];
  const float* g2  = (const float*)d_in[13];
  const float* b2  = (const float*)d_in[14];
  const float* m2  = (const float*)d_in[15];
  const float* v2  = (const float*)d_in[16];
  const float* lw  = (const float*)d_in[17];
  const float* lb  = (const float*)d_in[18];
  const float* bw  = (const float*)d_in[19];
  const float* bb  = (const float*)d_in[20];
  float* out = (float*)d_out;

  char* ws = (char*)d_ws;
  size_t off = 0;
  auto alloc = [&](size_t bytes) {
    void* p = ws + off;
    off = (off + bytes + 255) & ~(size_t)255;
    return p;
  };
  unsigned short* pooled = (unsigned short*)alloc((size_t)MPAD * KP * 2);
  unsigned short* w1p    = (unsigned short*)alloc((size_t)N1 * KP * 2);
  unsigned short* w2b    = (unsigned short*)alloc((size_t)N1 * N1 * 2);
  unsigned short* w3b    = (unsigned short*)alloc((size_t)N3P * N1 * 2);
  unsigned short* a2     = (unsigned short*)alloc((size_t)MPAD * N1 * 2);
  unsigned short* shd    = (unsigned short*)alloc((size_t)MPAD * N1 * 2);
  float* fc3 = (float*)alloc((size_t)MPAD * N3P * 4);
  // union region: transposed maps (44.6 MB) live only until roi_align2;
  // split-K partials (64 MB) written after — alias them.
  char* ub = (char*)alloc((size_t)KSPLIT * MPAD * N1 * 4);  // 64 MB
  unsigned short* f2t = (unsigned short*)ub;
  unsigned short* f3t = (unsigned short*)(ub + 33554432);
  unsigned short* f4t = (unsigned short*)(ub + 33554432 + 8388608);
  unsigned short* f5t = (unsigned short*)(ub + 33554432 + 8388608 + 2097152);
  float* part = (float*)ub;
  int* perm = (int*)alloc(2048 * 4);
  float* s1  = (float*)alloc(1024 * 4);
  float* t1  = (float*)alloc(1024 * 4);
  float* s2  = (float*)alloc(1024 * 4);
  float* t2  = (float*)alloc(1024 * 4);
  float* b3  = (float*)alloc(N3P * 4);

  prep_all<<<5570, 256, 0, stream>>>(c1w, c2w, lw, bw,
                                     c1b, g1, b1, m1, v1, c2b, g2, b2, m2, v2,
                                     lb, bb, roi, w1p, w2b, w3b,
                                     s1, t1, s2, t2, b3, perm);

  transpose_all<<<1360, 256, 0, stream>>>(p2, p3, p4, p5, f2t, f3t, f4t, f5t);

  roi_align2<<<MPAD, 256, 0, stream>>>(f2t, f3t, f4t, f5t, roi, perm, pooled);

  // GEMM1: [2048 x 12544] x [1024 x 12544]^T split-K=8 -> part
  gemm1_sk<<<dim3(N1 / 128, MPAD / 128, KSPLIT), 256, 0, stream>>>(pooled, w1p, part);
  reduce_sk<<<MPAD, 256, 0, stream>>>(part, perm, s1, t1, a2);

  // GEMM2: [2048 x 1024] x [1024 x 1024]^T -> BN2+ReLU -> shd (bf16)
  gemm_bt<1><<<dim3(N1 / 64, MPAD / 64), 256, 0, stream>>>(
      a2, w2b, MPAD, N1, N1, s2, t2, shd, nullptr, NROI, N1);
  // GEMM3: [2048 x 1024] x [448 x 1024]^T + bias -> fc3 (f32)
  gemm_bt<2><<<dim3(N3P / 64, MPAD / 64), 256, 0, stream>>>(
      shd, w3b, MPAD, N3P, N1, nullptr, b3, nullptr, fc3, NROI, N3P);

  head<<<NROI, 64, 0, stream>>>(fc3, out);
}

// Round 5
// 361.710 us; speedup vs baseline: 1.1165x; 1.1165x over previous
//
#include <hip/hip_runtime.h>
#include <stdint.h>

#define NROI 2000
#define MPAD 2048
#define KP   12544   // 256*49
#define N1   1024
#define NCLS 81
#define NBOX 324
#define N3   405
#define N3P  448
#define BN_EPS 0.001f
#define KSPLIT 8
#define KC    1568   // KP/KSPLIT = 24*64 + 32

typedef __attribute__((ext_vector_type(8))) short bf16x8;
typedef __attribute__((ext_vector_type(4))) float f32x4;

__device__ inline unsigned short f2bf(float f) {
  union { float f; unsigned u; } v; v.f = f;
  unsigned r = v.u + 0x7fffu + ((v.u >> 16) & 1u);
  return (unsigned short)(r >> 16);
}

__device__ inline float bf2f(unsigned short h) {
  union { unsigned u; float f; } v; v.u = (unsigned)h << 16; return v.f;
}

__device__ inline void gld16(const unsigned short* g, unsigned short* l) {
  __builtin_amdgcn_global_load_lds(
      (const __attribute__((address_space(1))) void*)g,
      (__attribute__((address_space(3))) void*)l, 16, 0, 0);
}

// =================== prep_all: all one-time param prep =====================
// blocks [0,1024): repack conv1_w -> w1p [o][hw*256+c] bf16
// blocks [1024,5120): cvt conv2_w -> bf16
// blocks [5120,5568): pack logits_w+bbox_w -> w3b bf16 (448 rows)
// block 5568: BN folding + bias concat
__global__ __launch_bounds__(256) void prep_all(
    const float* __restrict__ c1w, const float* __restrict__ c2w,
    const float* __restrict__ lw, const float* __restrict__ bw,
    const float* c1b, const float* g1, const float* b1, const float* m1, const float* v1,
    const float* c2b, const float* g2, const float* b2, const float* m2, const float* v2,
    const float* lb, const float* bb,
    unsigned short* __restrict__ w1p, unsigned short* __restrict__ w2b,
    unsigned short* __restrict__ w3b,
    float* s1, float* t1, float* s2, float* t2, float* b3) {
  __shared__ unsigned short s[KP];
  int b = blockIdx.x;
  int t = threadIdx.x;
  if (b < 1024) {
    // repack_w1: [o][c][hw] -> [o][hw*256+c]
    const float* src = c1w + (size_t)b * KP;
    for (int j = t; j < KP; j += 256) s[j] = f2bf(src[j]);  // s[c*49+hw]
    __syncthreads();
    unsigned short* dst = w1p + (size_t)b * KP;
    int lane = t & 63, w = t >> 6;
    int c4 = lane * 4;
    for (int j = w; j < 49; j += 4) {
      ushort4 o;
      o.x = s[(c4 + 0) * 49 + j];
      o.y = s[(c4 + 1) * 49 + j];
      o.z = s[(c4 + 2) * 49 + j];
      o.w = s[(c4 + 3) * 49 + j];
      *(ushort4*)(dst + j * 256 + c4) = o;
    }
  } else if (b < 5120) {
    int j = (b - 1024) * 256 + t;
    w2b[j] = f2bf(c2w[j]);
  } else if (b < 5568) {
    int row = b - 5120;
    for (int k = t; k < 1024; k += 256) {
      float v = (row < NCLS) ? lw[row * 1024 + k]
                             : (row < N3 ? bw[(row - NCLS) * 1024 + k] : 0.0f);
      w3b[row * 1024 + k] = f2bf(v);
    }
  } else {
    for (int i = t; i < 1024; i += 256) {
      float sc = g1[i] * rsqrtf(v1[i] + BN_EPS);
      s1[i] = sc;
      t1[i] = (c1b[i] - m1[i]) * sc + b1[i];
      float ss = g2[i] * rsqrtf(v2[i] + BN_EPS);
      s2[i] = ss;
      t2[i] = (c2b[i] - m2[i]) * ss + b2[i];
    }
    for (int i = t; i < N3P; i += 256)
      b3[i] = (i < NCLS) ? lb[i] : (i < N3 ? bb[i - NCLS] : 0.0f);
  }
}

// =================== fmap transposes: [256][HW] f32 -> [HW][256] bf16 ======
// Vectorized: float4 global loads, ushort4 LDS reads + global stores.
__global__ __launch_bounds__(256) void transpose_all(
    const float* __restrict__ p2, const float* __restrict__ p3,
    const float* __restrict__ p4, const float* __restrict__ p5,
    unsigned short* __restrict__ f2t, unsigned short* __restrict__ f3t,
    unsigned short* __restrict__ f4t, unsigned short* __restrict__ f5t) {
  __shared__ unsigned short s[64][260];  // 260 shorts: 8B-aligned rows
  int b = blockIdx.x;
  const float* src;
  unsigned short* dst;
  int HW;
  if (b < 1024)      { src = p2; dst = f2t; HW = 65536; }
  else if (b < 1280) { b -= 1024; src = p3; dst = f3t; HW = 16384; }
  else if (b < 1344) { b -= 1280; src = p4; dst = f4t; HW = 4096; }
  else               { b -= 1344; src = p5; dst = f5t; HW = 1024; }
  int p0 = b * 64;
  int t = threadIdx.x;
  int lane = t & 63, w = t >> 6;
  int px0 = (lane & 15) * 4;
#pragma unroll 4
  for (int it = 0; it < 16; ++it) {
    int c = w * 64 + it * 4 + (lane >> 4);
    float4 v = *(const float4*)(src + (size_t)c * HW + p0 + px0);
    s[px0 + 0][c] = f2bf(v.x);
    s[px0 + 1][c] = f2bf(v.y);
    s[px0 + 2][c] = f2bf(v.z);
    s[px0 + 3][c] = f2bf(v.w);
  }
  __syncthreads();
  int c4 = lane * 4;
#pragma unroll 4
  for (int i = 0; i < 16; ++i) {
    int p = w * 16 + i;
    ushort4 o = *(const ushort4*)&s[p][c4];
    *(ushort4*)(dst + (size_t)(p0 + p) * 256 + c4) = o;
  }
}

// =================== ROI Align: gather from [HW][256] bf16 maps ============
// Vectorized: each lane handles 4 channels (ushort4 loads/stores); each wave
// handles every 4th of the 49 positions.
__global__ __launch_bounds__(256) void roi_align2(
    const unsigned short* __restrict__ f2t, const unsigned short* __restrict__ f3t,
    const unsigned short* __restrict__ f4t, const unsigned short* __restrict__ f5t,
    const float* __restrict__ rois, unsigned short* __restrict__ pooled) {
  int n = blockIdx.x;
  int t = threadIdx.x;
  int lane = t & 63, w = t >> 6;
  int c0 = lane * 4;
  unsigned short* out = pooled + (size_t)n * KP;
  if (n >= NROI) {
    for (int p = w; p < 49; p += 4)
      *(ushort4*)(out + p * 256 + c0) = make_ushort4(0, 0, 0, 0);
    return;
  }
  float x1 = rois[n * 4 + 0], y1 = rois[n * 4 + 1];
  float x2 = rois[n * 4 + 2], y2 = rois[n * 4 + 3];
  float area = (y2 - y1) * (x2 - x1);
  float lvl_f = rintf(log2f(sqrtf(area) / 224.0f)) + 4.0f;
  lvl_f = fminf(fmaxf(lvl_f, 2.0f), 5.0f);
  int lvl = (int)lvl_f;
  const unsigned short* f;
  int H;
  if (lvl == 2)      { f = f2t; H = 256; }
  else if (lvl == 3) { f = f3t; H = 128; }
  else if (lvl == 4) { f = f4t; H = 64;  }
  else               { f = f5t; H = 32;  }
  int W = H;
  const float inv = 1.0f / 1024.0f;
  float yn1 = y1 * inv, xn1 = x1 * inv, yn2 = y2 * inv, xn2 = x2 * inv;
  float hs = (yn2 - yn1) * (H - 1);
  float ws = (xn2 - xn1) * (W - 1);
  float yb = yn1 * (H - 1);
  float xb = xn1 * (W - 1);

  for (int p = w; p < 49; p += 4) {
    int py = p / 7, px = p - py * 7;
    float ysv = yb + ((float)py / 6.0f) * hs;
    float xsv = xb + ((float)px / 6.0f) * ws;
    float y0f = floorf(ysv), x0f = floorf(xsv);
    float ly = ysv - y0f, lx = xsv - x0f;
    int y0 = min(max((int)y0f, 0), H - 1);
    int y1i = min(y0 + 1, H - 1);
    int x0 = min(max((int)x0f, 0), W - 1);
    int x1i = min(x0 + 1, W - 1);
    ushort4 v00 = *(const ushort4*)(f + ((size_t)y0 * W + x0) * 256 + c0);
    ushort4 v01 = *(const ushort4*)(f + ((size_t)y0 * W + x1i) * 256 + c0);
    ushort4 v10 = *(const ushort4*)(f + ((size_t)y1i * W + x0) * 256 + c0);
    ushort4 v11 = *(const ushort4*)(f + ((size_t)y1i * W + x1i) * 256 + c0);
    ushort4 o;
    {
      float a = bf2f(v00.x), bq = bf2f(v01.x), cq = bf2f(v10.x), d = bf2f(v11.x);
      float top = a + lx * (bq - a), bot = cq + lx * (d - cq);
      o.x = f2bf(top + ly * (bot - top));
    }
    {
      float a = bf2f(v00.y), bq = bf2f(v01.y), cq = bf2f(v10.y), d = bf2f(v11.y);
      float top = a + lx * (bq - a), bot = cq + lx * (d - cq);
      o.y = f2bf(top + ly * (bot - top));
    }
    {
      float a = bf2f(v00.z), bq = bf2f(v01.z), cq = bf2f(v10.z), d = bf2f(v11.z);
      float top = a + lx * (bq - a), bot = cq + lx * (d - cq);
      o.z = f2bf(top + ly * (bot - top));
    }
    {
      float a = bf2f(v00.w), bq = bf2f(v01.w), cq = bf2f(v10.w), d = bf2f(v11.w);
      float top = a + lx * (bq - a), bot = cq + lx * (d - cq);
      o.w = f2bf(top + ly * (bot - top));
    }
    *(ushort4*)(out + p * 256 + c0) = o;
  }
}

// =================== GEMM1 split-K: 128x128 tile, BK=64, XCD swizzle =======
// grid = 1024 1D blocks. kz = bid&7 (one K-slice per XCD for L2 residency),
// n-fast within XCD so the 3.2 MB B-chunk stays L2-hot.
__global__ __launch_bounds__(256) void gemm1_sk(
    const unsigned short* __restrict__ A, const unsigned short* __restrict__ B,
    float* __restrict__ part) {
  __shared__ unsigned short As[128 * 64];  // 16 KB
  __shared__ unsigned short Bs[128 * 64];
  int bid = blockIdx.x;
  int kz = bid & 7;
  int u = bid >> 3;
  int bn0 = (u & 7) * 128;
  int bm0 = (u >> 3) * 128;
  int t = threadIdx.x;
  int lane = t & 63, w = t >> 6;
  int wm = (w & 1) * 64, wn = (w >> 1) * 64;
  int ln = lane & 15, q = lane >> 4;

  // BK=64 staging: call i stages rows i*32 + (t>>3), k-seg t&7
  const unsigned short* ga = A + (size_t)(bm0 + (t >> 3)) * KP + kz * KC + (t & 7) * 8;
  const unsigned short* gb = B + (size_t)(bn0 + (t >> 3)) * KP + kz * KC + (t & 7) * 8;
  unsigned short* la = &As[t * 8];
  unsigned short* lb = &Bs[t * 8];

  f32x4 acc[4][4] = {};

  for (int k0 = 0; k0 < 1536; k0 += 64) {
#pragma unroll
    for (int i = 0; i < 4; ++i) {
      gld16(ga + k0 + (size_t)(i * 32) * KP, la + i * 2048);
      gld16(gb + k0 + (size_t)(i * 32) * KP, lb + i * 2048);
    }
    __syncthreads();
#pragma unroll
    for (int h = 0; h < 2; ++h) {
      bf16x8 af[4], bfr[4];
#pragma unroll
      for (int i = 0; i < 4; ++i) {
        af[i]  = *(const bf16x8*)&As[(wm + i * 16 + ln) * 64 + h * 32 + q * 8];
        bfr[i] = *(const bf16x8*)&Bs[(wn + i * 16 + ln) * 64 + h * 32 + q * 8];
      }
#pragma unroll
      for (int i = 0; i < 4; ++i)
#pragma unroll
        for (int j = 0; j < 4; ++j)
          acc[i][j] = __builtin_amdgcn_mfma_f32_16x16x32_bf16(af[i], bfr[j], acc[i][j], 0, 0, 0);
    }
    __syncthreads();
  }
  {  // tail BK=32 (KC = 24*64 + 32)
    const unsigned short* ga2 = A + (size_t)(bm0 + (t >> 2)) * KP + kz * KC + 1536 + (t & 3) * 8;
    const unsigned short* gb2 = B + (size_t)(bn0 + (t >> 2)) * KP + kz * KC + 1536 + (t & 3) * 8;
    gld16(ga2, &As[t * 8]);
    gld16(ga2 + (size_t)64 * KP, &As[t * 8 + 2048]);
    gld16(gb2, &Bs[t * 8]);
    gld16(gb2 + (size_t)64 * KP, &Bs[t * 8 + 2048]);
    __syncthreads();
    bf16x8 af[4], bfr[4];
#pragma unroll
    for (int i = 0; i < 4; ++i) {
      af[i]  = *(const bf16x8*)&As[(wm + i * 16 + ln) * 32 + q * 8];
      bfr[i] = *(const bf16x8*)&Bs[(wn + i * 16 + ln) * 32 + q * 8];
    }
#pragma unroll
    for (int i = 0; i < 4; ++i)
#pragma unroll
      for (int j = 0; j < 4; ++j)
        acc[i][j] = __builtin_amdgcn_mfma_f32_16x16x32_bf16(af[i], bfr[j], acc[i][j], 0, 0, 0);
  }

  float* po = part + (size_t)kz * MPAD * N1;
#pragma unroll
  for (int i = 0; i < 4; ++i)
#pragma unroll
    for (int j = 0; j < 4; ++j)
#pragma unroll
      for (int r = 0; r < 4; ++r) {
        int m = bm0 + wm + i * 16 + q * 4 + r;
        int n = bn0 + wn + j * 16 + ln;
        po[(size_t)m * N1 + n] = acc[i][j][r];
      }
}

// =================== split-K reduce + BN1 + ReLU + bf16 ====================
__global__ void reduce_sk(const float* __restrict__ part,
                          const float* __restrict__ sc, const float* __restrict__ sh,
                          unsigned short* __restrict__ outb) {
  const size_t P = (size_t)MPAD * N1;
  int m = blockIdx.x;
  int t = threadIdx.x;  // 0..255, covers 1024 cols as float4
  float4 v = {0.f, 0.f, 0.f, 0.f};
#pragma unroll
  for (int kz = 0; kz < KSPLIT; ++kz) {
    const float4* pk = (const float4*)(part + kz * P + (size_t)m * N1);
    float4 u = pk[t];
    v.x += u.x; v.y += u.y; v.z += u.z; v.w += u.w;
  }
  int n0 = t * 4;
  ushort4 o;
  if (m < NROI) {
    o.x = f2bf(fmaxf(v.x * sc[n0 + 0] + sh[n0 + 0], 0.0f));
    o.y = f2bf(fmaxf(v.y * sc[n0 + 1] + sh[n0 + 1], 0.0f));
    o.z = f2bf(fmaxf(v.z * sc[n0 + 2] + sh[n0 + 2], 0.0f));
    o.w = f2bf(fmaxf(v.w * sc[n0 + 3] + sh[n0 + 3], 0.0f));
  } else {
    o = make_ushort4(0, 0, 0, 0);
  }
  *(ushort4*)(outb + (size_t)m * N1 + n0) = o;
}

// =================== bf16 MFMA GEMM (64x64 tile), B^T input ================
template <int MODE>
__global__ __launch_bounds__(256) void gemm_bt(
    const unsigned short* __restrict__ A, const unsigned short* __restrict__ B,
    int M, int N, int K,
    const float* __restrict__ sc, const float* __restrict__ sh,
    unsigned short* __restrict__ outb, float* __restrict__ outf,
    int validM, int ldo) {
  __shared__ unsigned short As[64 * 32];
  __shared__ unsigned short Bs[64 * 32];
  int bm0 = blockIdx.y * 64;
  int bn0 = blockIdx.x * 64;
  int t = threadIdx.x;
  int lane = t & 63, w = t >> 6;
  int wm = (w & 1) * 32, wn = (w >> 1) * 32;
  int ln = lane & 15, q = lane >> 4;

  const unsigned short* ga = A + (size_t)(bm0 + (t >> 2)) * K + (t & 3) * 8;
  const unsigned short* gb = B + (size_t)(bn0 + (t >> 2)) * K + (t & 3) * 8;
  unsigned short* la = &As[t * 8];
  unsigned short* lb = &Bs[t * 8];

  f32x4 acc00 = {0.f, 0.f, 0.f, 0.f}, acc01 = {0.f, 0.f, 0.f, 0.f};
  f32x4 acc10 = {0.f, 0.f, 0.f, 0.f}, acc11 = {0.f, 0.f, 0.f, 0.f};

  for (int k0 = 0; k0 < K; k0 += 32) {
    gld16(ga + k0, la);
    gld16(gb + k0, lb);
    __syncthreads();
    bf16x8 a0 = *(const bf16x8*)&As[(wm + ln) * 32 + q * 8];
    bf16x8 a1 = *(const bf16x8*)&As[(wm + 16 + ln) * 32 + q * 8];
    bf16x8 b0 = *(const bf16x8*)&Bs[(wn + ln) * 32 + q * 8];
    bf16x8 b1 = *(const bf16x8*)&Bs[(wn + 16 + ln) * 32 + q * 8];
    acc00 = __builtin_amdgcn_mfma_f32_16x16x32_bf16(a0, b0, acc00, 0, 0, 0);
    acc01 = __builtin_amdgcn_mfma_f32_16x16x32_bf16(a0, b1, acc01, 0, 0, 0);
    acc10 = __builtin_amdgcn_mfma_f32_16x16x32_bf16(a1, b0, acc10, 0, 0, 0);
    acc11 = __builtin_amdgcn_mfma_f32_16x16x32_bf16(a1, b1, acc11, 0, 0, 0);
    __syncthreads();
  }

  f32x4 accs[2][2] = {{acc00, acc01}, {acc10, acc11}};
#pragma unroll
  for (int i = 0; i < 2; ++i)
#pragma unroll
    for (int j = 0; j < 2; ++j)
#pragma unroll
      for (int r = 0; r < 4; ++r) {
        int m = bm0 + wm + i * 16 + q * 4 + r;
        int n = bn0 + wn + j * 16 + ln;
        float v = accs[i][j][r];
        if (MODE == 1) {
          float o = fmaxf(v * sc[n] + sh[n], 0.0f);
          outb[(size_t)m * ldo + n] = (m < validM) ? f2bf(o) : (unsigned short)0;
        } else {
          outf[(size_t)m * ldo + n] = v + sh[n];
        }
      }
}

// =================== softmax + output scatter ===============================
__global__ void head(const float* __restrict__ fc3, float* __restrict__ out) {
  int r = blockIdx.x;
  int t = threadIdx.x;  // 0..63
  const float* row = fc3 + (size_t)r * N3P;
  float v0 = (t < NCLS) ? row[t] : -INFINITY;
  float v1 = (t + 64 < NCLS) ? row[t + 64] : -INFINITY;
  float m = fmaxf(v0, v1);
#pragma unroll
  for (int o = 32; o > 0; o >>= 1) m = fmaxf(m, __shfl_xor(m, o, 64));
  float e0 = (t < NCLS) ? expf(v0 - m) : 0.0f;
  float e1 = (t + 64 < NCLS) ? expf(v1 - m) : 0.0f;
  float s = e0 + e1;
#pragma unroll
  for (int o = 32; o > 0; o >>= 1) s += __shfl_xor(s, o, 64);
  float invs = 1.0f / s;
  float* ol = out + (size_t)r * NCLS;
  float* op = out + 162000 + (size_t)r * NCLS;
  float* ob = out + 324000 + (size_t)r * NBOX;
  if (t < NCLS) { ol[t] = v0; op[t] = e0 * invs; }
  if (t + 64 < NCLS) { ol[t + 64] = v1; op[t + 64] = e1 * invs; }
  for (int j = t; j < NBOX; j += 64) ob[j] = row[NCLS + j];
}

extern "C" void kernel_launch(void* const* d_in, const int* in_sizes, int n_in,
                              void* d_out, int out_size, void* d_ws, size_t ws_size,
                              hipStream_t stream) {
  const float* p2  = (const float*)d_in[0];
  const float* p3  = (const float*)d_in[1];
  const float* p4  = (const float*)d_in[2];
  const float* p5  = (const float*)d_in[3];
  const float* roi = (const float*)d_in[4];
  const float* c1w = (const float*)d_in[5];
  const float* c1b = (const float*)d_in[6];
  const float* g1  = (const float*)d_in[7];
  const float* b1  = (const float*)d_in[8];
  const float* m1  = (const float*)d_in[9];
  const float* v1  = (const float*)d_in[10];
  const float* c2w = (const float*)d_in[11];
  const float* c2b = (const float*)d_in[12];
  const float* g2  = (const float*)d_in[13];
  const float* b2  = (const float*)d_in[14];
  const float* m2  = (const float*)d_in[15];
  const float* v2  = (const float*)d_in[16];
  const float* lw  = (const float*)d_in[17];
  const float* lb  = (const float*)d_in[18];
  const float* bw  = (const float*)d_in[19];
  const float* bb  = (const float*)d_in[20];
  float* out = (float*)d_out;

  char* ws = (char*)d_ws;
  size_t off = 0;
  auto alloc = [&](size_t bytes) {
    void* p = ws + off;
    off = (off + bytes + 255) & ~(size_t)255;
    return p;
  };
  unsigned short* pooled = (unsigned short*)alloc((size_t)MPAD * KP * 2);
  unsigned short* w1p    = (unsigned short*)alloc((size_t)N1 * KP * 2);
  unsigned short* w2b    = (unsigned short*)alloc((size_t)N1 * N1 * 2);
  unsigned short* w3b    = (unsigned short*)alloc((size_t)N3P * N1 * 2);
  unsigned short* a2     = (unsigned short*)alloc((size_t)MPAD * N1 * 2);
  unsigned short* shd    = (unsigned short*)alloc((size_t)MPAD * N1 * 2);
  float* fc3 = (float*)alloc((size_t)MPAD * N3P * 4);
  // union region: transposed maps (44.6 MB) live only until roi_align2;
  // split-K partials (64 MB) written after — alias them.
  char* ub = (char*)alloc((size_t)KSPLIT * MPAD * N1 * 4);  // 64 MB
  unsigned short* f2t = (unsigned short*)ub;
  unsigned short* f3t = (unsigned short*)(ub + 33554432);
  unsigned short* f4t = (unsigned short*)(ub + 33554432 + 8388608);
  unsigned short* f5t = (unsigned short*)(ub + 33554432 + 8388608 + 2097152);
  float* part = (float*)ub;
  float* s1  = (float*)alloc(1024 * 4);
  float* t1  = (float*)alloc(1024 * 4);
  float* s2  = (float*)alloc(1024 * 4);
  float* t2  = (float*)alloc(1024 * 4);
  float* b3  = (float*)alloc(N3P * 4);

  prep_all<<<5569, 256, 0, stream>>>(c1w, c2w, lw, bw,
                                     c1b, g1, b1, m1, v1, c2b, g2, b2, m2, v2,
                                     lb, bb, w1p, w2b, w3b, s1, t1, s2, t2, b3);

  transpose_all<<<1360, 256, 0, stream>>>(p2, p3, p4, p5, f2t, f3t, f4t, f5t);

  roi_align2<<<MPAD, 256, 0, stream>>>(f2t, f3t, f4t, f5t, roi, pooled);

  // GEMM1: [2048 x 12544] x [1024 x 12544]^T split-K=8, XCD-swizzled
  gemm1_sk<<<1024, 256, 0, stream>>>(pooled, w1p, part);
  reduce_sk<<<MPAD, 256, 0, stream>>>(part, s1, t1, a2);

  // GEMM2: [2048 x 1024] x [1024 x 1024]^T -> BN2+ReLU -> shd (bf16)
  gemm_bt<1><<<dim3(N1 / 64, MPAD / 64), 256, 0, stream>>>(
      a2, w2b, MPAD, N1, N1, s2, t2, shd, nullptr, NROI, N1);
  // GEMM3: [2048 x 1024] x [448 x 1024]^T + bias -> fc3 (f32)
  gemm_bt<2><<<dim3(N3P / 64, MPAD / 64), 256, 0, stream>>>(
      shd, w3b, MPAD, N3P, N1, nullptr, b3, nullptr, fc3, NROI, N3P);

  head<<<NROI, 64, 0, stream>>>(fc3, out);
}

// Round 6
// 352.847 us; speedup vs baseline: 1.1445x; 1.0251x over previous
//
#include <hip/hip_runtime.h>
#include <stdint.h>

#define NROI 2000
#define MPAD 2048
#define KP   12544   // 256*49
#define N1   1024
#define NCLS 81
#define NBOX 324
#define N3   405
#define N3P  448
#define BN_EPS 0.001f
#define KSPLIT 8
#define KC    1568   // KP/KSPLIT = 24*64 + 32

typedef __attribute__((ext_vector_type(8))) short bf16x8;
typedef __attribute__((ext_vector_type(4))) float f32x4;

__device__ inline unsigned short f2bf(float f) {
  union { float f; unsigned u; } v; v.f = f;
  unsigned r = v.u + 0x7fffu + ((v.u >> 16) & 1u);
  return (unsigned short)(r >> 16);
}

__device__ inline float bf2f(unsigned short h) {
  union { unsigned u; float f; } v; v.u = (unsigned)h << 16; return v.f;
}

__device__ inline void gld16(const unsigned short* g, unsigned short* l) {
  __builtin_amdgcn_global_load_lds(
      (const __attribute__((address_space(1))) void*)g,
      (__attribute__((address_space(3))) void*)l, 16, 0, 0);
}

// =================== prep_all: all one-time param prep =====================
__global__ __launch_bounds__(256) void prep_all(
    const float* __restrict__ c1w, const float* __restrict__ c2w,
    const float* __restrict__ lw, const float* __restrict__ bw,
    const float* c1b, const float* g1, const float* b1, const float* m1, const float* v1,
    const float* c2b, const float* g2, const float* b2, const float* m2, const float* v2,
    const float* lb, const float* bb,
    unsigned short* __restrict__ w1p, unsigned short* __restrict__ w2b,
    unsigned short* __restrict__ w3b,
    float* s1, float* t1, float* s2, float* t2, float* b3) {
  __shared__ unsigned short s[KP];
  int b = blockIdx.x;
  int t = threadIdx.x;
  if (b < 1024) {
    // repack_w1: [o][c][hw] -> [o][hw*256+c]
    const float* src = c1w + (size_t)b * KP;
    for (int j = t; j < KP; j += 256) s[j] = f2bf(src[j]);  // s[c*49+hw]
    __syncthreads();
    unsigned short* dst = w1p + (size_t)b * KP;
    int lane = t & 63, w = t >> 6;
    int c4 = lane * 4;
    for (int j = w; j < 49; j += 4) {
      ushort4 o;
      o.x = s[(c4 + 0) * 49 + j];
      o.y = s[(c4 + 1) * 49 + j];
      o.z = s[(c4 + 2) * 49 + j];
      o.w = s[(c4 + 3) * 49 + j];
      *(ushort4*)(dst + j * 256 + c4) = o;
    }
  } else if (b < 5120) {
    int j = (b - 1024) * 256 + t;
    w2b[j] = f2bf(c2w[j]);
  } else if (b < 5568) {
    int row = b - 5120;
    for (int k = t; k < 1024; k += 256) {
      float v = (row < NCLS) ? lw[row * 1024 + k]
                             : (row < N3 ? bw[(row - NCLS) * 1024 + k] : 0.0f);
      w3b[row * 1024 + k] = f2bf(v);
    }
  } else {
    for (int i = t; i < 1024; i += 256) {
      float sc = g1[i] * rsqrtf(v1[i] + BN_EPS);
      s1[i] = sc;
      t1[i] = (c1b[i] - m1[i]) * sc + b1[i];
      float ss = g2[i] * rsqrtf(v2[i] + BN_EPS);
      s2[i] = ss;
      t2[i] = (c2b[i] - m2[i]) * ss + b2[i];
    }
    for (int i = t; i < N3P; i += 256)
      b3[i] = (i < NCLS) ? lb[i] : (i < N3 ? bb[i - NCLS] : 0.0f);
  }
}

// =================== fmap transposes: [256][HW] f32 -> [HW][256] bf16 ======
__global__ __launch_bounds__(256) void transpose_all(
    const float* __restrict__ p2, const float* __restrict__ p3,
    const float* __restrict__ p4, const float* __restrict__ p5,
    unsigned short* __restrict__ f2t, unsigned short* __restrict__ f3t,
    unsigned short* __restrict__ f4t, unsigned short* __restrict__ f5t) {
  __shared__ unsigned short s[64][260];  // 260 shorts: 8B-aligned rows
  int b = blockIdx.x;
  const float* src;
  unsigned short* dst;
  int HW;
  if (b < 1024)      { src = p2; dst = f2t; HW = 65536; }
  else if (b < 1280) { b -= 1024; src = p3; dst = f3t; HW = 16384; }
  else if (b < 1344) { b -= 1280; src = p4; dst = f4t; HW = 4096; }
  else               { b -= 1344; src = p5; dst = f5t; HW = 1024; }
  int p0 = b * 64;
  int t = threadIdx.x;
  int lane = t & 63, w = t >> 6;
  int px0 = (lane & 15) * 4;
#pragma unroll 4
  for (int it = 0; it < 16; ++it) {
    int c = w * 64 + it * 4 + (lane >> 4);
    float4 v = *(const float4*)(src + (size_t)c * HW + p0 + px0);
    s[px0 + 0][c] = f2bf(v.x);
    s[px0 + 1][c] = f2bf(v.y);
    s[px0 + 2][c] = f2bf(v.z);
    s[px0 + 3][c] = f2bf(v.w);
  }
  __syncthreads();
  int c4 = lane * 4;
#pragma unroll 4
  for (int i = 0; i < 16; ++i) {
    int p = w * 16 + i;
    ushort4 o = *(const ushort4*)&s[p][c4];
    *(ushort4*)(dst + (size_t)(p0 + p) * 256 + c4) = o;
  }
}

// =================== ROI Align: gather from [HW][256] bf16 maps ============
__global__ __launch_bounds__(256) void roi_align2(
    const unsigned short* __restrict__ f2t, const unsigned short* __restrict__ f3t,
    const unsigned short* __restrict__ f4t, const unsigned short* __restrict__ f5t,
    const float* __restrict__ rois, unsigned short* __restrict__ pooled) {
  int n = blockIdx.x;
  int t = threadIdx.x;
  int lane = t & 63, w = t >> 6;
  int c0 = lane * 4;
  unsigned short* out = pooled + (size_t)n * KP;
  if (n >= NROI) {
    for (int p = w; p < 49; p += 4)
      *(ushort4*)(out + p * 256 + c0) = make_ushort4(0, 0, 0, 0);
    return;
  }
  float x1 = rois[n * 4 + 0], y1 = rois[n * 4 + 1];
  float x2 = rois[n * 4 + 2], y2 = rois[n * 4 + 3];
  float area = (y2 - y1) * (x2 - x1);
  float lvl_f = rintf(log2f(sqrtf(area) / 224.0f)) + 4.0f;
  lvl_f = fminf(fmaxf(lvl_f, 2.0f), 5.0f);
  int lvl = (int)lvl_f;
  const unsigned short* f;
  int H;
  if (lvl == 2)      { f = f2t; H = 256; }
  else if (lvl == 3) { f = f3t; H = 128; }
  else if (lvl == 4) { f = f4t; H = 64;  }
  else               { f = f5t; H = 32;  }
  int W = H;
  const float inv = 1.0f / 1024.0f;
  float yn1 = y1 * inv, xn1 = x1 * inv, yn2 = y2 * inv, xn2 = x2 * inv;
  float hs = (yn2 - yn1) * (H - 1);
  float ws = (xn2 - xn1) * (W - 1);
  float yb = yn1 * (H - 1);
  float xb = xn1 * (W - 1);

  for (int p = w; p < 49; p += 4) {
    int py = p / 7, px = p - py * 7;
    float ysv = yb + ((float)py / 6.0f) * hs;
    float xsv = xb + ((float)px / 6.0f) * ws;
    float y0f = floorf(ysv), x0f = floorf(xsv);
    float ly = ysv - y0f, lx = xsv - x0f;
    int y0 = min(max((int)y0f, 0), H - 1);
    int y1i = min(y0 + 1, H - 1);
    int x0 = min(max((int)x0f, 0), W - 1);
    int x1i = min(x0 + 1, W - 1);
    ushort4 v00 = *(const ushort4*)(f + ((size_t)y0 * W + x0) * 256 + c0);
    ushort4 v01 = *(const ushort4*)(f + ((size_t)y0 * W + x1i) * 256 + c0);
    ushort4 v10 = *(const ushort4*)(f + ((size_t)y1i * W + x0) * 256 + c0);
    ushort4 v11 = *(const ushort4*)(f + ((size_t)y1i * W + x1i) * 256 + c0);
    ushort4 o;
    {
      float a = bf2f(v00.x), bq = bf2f(v01.x), cq = bf2f(v10.x), d = bf2f(v11.x);
      float top = a + lx * (bq - a), bot = cq + lx * (d - cq);
      o.x = f2bf(top + ly * (bot - top));
    }
    {
      float a = bf2f(v00.y), bq = bf2f(v01.y), cq = bf2f(v10.y), d = bf2f(v11.y);
      float top = a + lx * (bq - a), bot = cq + lx * (d - cq);
      o.y = f2bf(top + ly * (bot - top));
    }
    {
      float a = bf2f(v00.z), bq = bf2f(v01.z), cq = bf2f(v10.z), d = bf2f(v11.z);
      float top = a + lx * (bq - a), bot = cq + lx * (d - cq);
      o.z = f2bf(top + ly * (bot - top));
    }
    {
      float a = bf2f(v00.w), bq = bf2f(v01.w), cq = bf2f(v10.w), d = bf2f(v11.w);
      float top = a + lx * (bq - a), bot = cq + lx * (d - cq);
      o.w = f2bf(top + ly * (bot - top));
    }
    *(ushort4*)(out + p * 256 + c0) = o;
  }
}

// =================== GEMM1 split-K: 128x128, BK=64, XCD + LDS-XOR swizzle ==
// LDS slot j of row r holds global k-seg (j ^ (r&7)); reader uses
// slot = (h*4+q) ^ (ln&7) -> each 8-lane phase covers all 32 banks.
__global__ __launch_bounds__(256) void gemm1_sk(
    const unsigned short* __restrict__ A, const unsigned short* __restrict__ B,
    float* __restrict__ part) {
  __shared__ unsigned short As[128 * 64];  // 16 KB
  __shared__ unsigned short Bs[128 * 64];
  int bid = blockIdx.x;
  int kz = bid & 7;
  int u = bid >> 3;
  int bn0 = (u & 7) * 128;
  int bm0 = (u >> 3) * 128;
  int t = threadIdx.x;
  int lane = t & 63, w = t >> 6;
  int wm = (w & 1) * 64, wn = (w >> 1) * 64;
  int ln = lane & 15, q = lane >> 4;

  int r8 = t >> 3, j8 = t & 7;
  int sj = j8 ^ (r8 & 7);  // XOR source swizzle
  const unsigned short* ga = A + (size_t)(bm0 + r8) * KP + kz * KC + sj * 8;
  const unsigned short* gb = B + (size_t)(bn0 + r8) * KP + kz * KC + sj * 8;
  unsigned short* la = &As[t * 8];
  unsigned short* lb = &Bs[t * 8];
  int e = ln & 7;

  f32x4 acc[4][4] = {};

  for (int k0 = 0; k0 < 1536; k0 += 64) {
#pragma unroll
    for (int i = 0; i < 4; ++i) {
      gld16(ga + k0 + (size_t)(i * 32) * KP, la + i * 2048);
      gld16(gb + k0 + (size_t)(i * 32) * KP, lb + i * 2048);
    }
    __syncthreads();
#pragma unroll
    for (int h = 0; h < 2; ++h) {
      int slot = ((h * 4 + q) ^ e) * 8;
      bf16x8 af[4], bfr[4];
#pragma unroll
      for (int i = 0; i < 4; ++i) {
        af[i]  = *(const bf16x8*)&As[(wm + i * 16 + ln) * 64 + slot];
        bfr[i] = *(const bf16x8*)&Bs[(wn + i * 16 + ln) * 64 + slot];
      }
#pragma unroll
      for (int i = 0; i < 4; ++i)
#pragma unroll
        for (int j = 0; j < 4; ++j)
          acc[i][j] = __builtin_amdgcn_mfma_f32_16x16x32_bf16(af[i], bfr[j], acc[i][j], 0, 0, 0);
    }
    __syncthreads();
  }
  {  // tail BK=32 (KC = 24*64 + 32), unswizzled layout
    const unsigned short* ga2 = A + (size_t)(bm0 + (t >> 2)) * KP + kz * KC + 1536 + (t & 3) * 8;
    const unsigned short* gb2 = B + (size_t)(bn0 + (t >> 2)) * KP + kz * KC + 1536 + (t & 3) * 8;
    gld16(ga2, &As[t * 8]);
    gld16(ga2 + (size_t)64 * KP, &As[t * 8 + 2048]);
    gld16(gb2, &Bs[t * 8]);
    gld16(gb2 + (size_t)64 * KP, &Bs[t * 8 + 2048]);
    __syncthreads();
    bf16x8 af[4], bfr[4];
#pragma unroll
    for (int i = 0; i < 4; ++i) {
      af[i]  = *(const bf16x8*)&As[(wm + i * 16 + ln) * 32 + q * 8];
      bfr[i] = *(const bf16x8*)&Bs[(wn + i * 16 + ln) * 32 + q * 8];
    }
#pragma unroll
    for (int i = 0; i < 4; ++i)
#pragma unroll
      for (int j = 0; j < 4; ++j)
        acc[i][j] = __builtin_amdgcn_mfma_f32_16x16x32_bf16(af[i], bfr[j], acc[i][j], 0, 0, 0);
  }

  float* po = part + (size_t)kz * MPAD * N1;
#pragma unroll
  for (int i = 0; i < 4; ++i)
#pragma unroll
    for (int j = 0; j < 4; ++j)
#pragma unroll
      for (int r = 0; r < 4; ++r) {
        int m = bm0 + wm + i * 16 + q * 4 + r;
        int n = bn0 + wn + j * 16 + ln;
        po[(size_t)m * N1 + n] = acc[i][j][r];
      }
}

// =================== split-K reduce + BN1 + ReLU + bf16 ====================
__global__ void reduce_sk(const float* __restrict__ part,
                          const float* __restrict__ sc, const float* __restrict__ sh,
                          unsigned short* __restrict__ outb) {
  const size_t P = (size_t)MPAD * N1;
  int m = blockIdx.x;
  int t = threadIdx.x;
  float4 v = {0.f, 0.f, 0.f, 0.f};
#pragma unroll
  for (int kz = 0; kz < KSPLIT; ++kz) {
    const float4* pk = (const float4*)(part + kz * P + (size_t)m * N1);
    float4 u = pk[t];
    v.x += u.x; v.y += u.y; v.z += u.z; v.w += u.w;
  }
  int n0 = t * 4;
  ushort4 o;
  if (m < NROI) {
    o.x = f2bf(fmaxf(v.x * sc[n0 + 0] + sh[n0 + 0], 0.0f));
    o.y = f2bf(fmaxf(v.y * sc[n0 + 1] + sh[n0 + 1], 0.0f));
    o.z = f2bf(fmaxf(v.z * sc[n0 + 2] + sh[n0 + 2], 0.0f));
    o.w = f2bf(fmaxf(v.w * sc[n0 + 3] + sh[n0 + 3], 0.0f));
  } else {
    o = make_ushort4(0, 0, 0, 0);
  }
  *(ushort4*)(outb + (size_t)m * N1 + n0) = o;
}

// =================== bf16 MFMA GEMM (64x64 tile, BK=64, swizzled) ==========
// K must be a multiple of 64. MODE 1: bf16 relu-BN out; MODE 2: f32 +bias out.
template <int MODE>
__global__ __launch_bounds__(256) void gemm_bt(
    const unsigned short* __restrict__ A, const unsigned short* __restrict__ B,
    int M, int N, int K,
    const float* __restrict__ sc, const float* __restrict__ sh,
    unsigned short* __restrict__ outb, float* __restrict__ outf,
    int validM, int ldo) {
  __shared__ unsigned short As[64 * 64];  // 8 KB
  __shared__ unsigned short Bs[64 * 64];
  int bm0 = blockIdx.y * 64;
  int bn0 = blockIdx.x * 64;
  int t = threadIdx.x;
  int lane = t & 63, w = t >> 6;
  int wm = (w & 1) * 32, wn = (w >> 1) * 32;
  int ln = lane & 15, q = lane >> 4;

  int r8 = t >> 3, j8 = t & 7;
  int sj = j8 ^ (r8 & 7);
  const unsigned short* ga = A + (size_t)(bm0 + r8) * K + sj * 8;
  const unsigned short* gb = B + (size_t)(bn0 + r8) * K + sj * 8;
  unsigned short* la = &As[t * 8];
  unsigned short* lb = &Bs[t * 8];
  int e = ln & 7;

  f32x4 acc00 = {0.f, 0.f, 0.f, 0.f}, acc01 = {0.f, 0.f, 0.f, 0.f};
  f32x4 acc10 = {0.f, 0.f, 0.f, 0.f}, acc11 = {0.f, 0.f, 0.f, 0.f};

  for (int k0 = 0; k0 < K; k0 += 64) {
    gld16(ga + k0, la);
    gld16(ga + k0 + (size_t)32 * K, la + 2048);
    gld16(gb + k0, lb);
    gld16(gb + k0 + (size_t)32 * K, lb + 2048);
    __syncthreads();
#pragma unroll
    for (int h = 0; h < 2; ++h) {
      int slot = ((h * 4 + q) ^ e) * 8;
      bf16x8 a0 = *(const bf16x8*)&As[(wm + ln) * 64 + slot];
      bf16x8 a1 = *(const bf16x8*)&As[(wm + 16 + ln) * 64 + slot];
      bf16x8 b0 = *(const bf16x8*)&Bs[(wn + ln) * 64 + slot];
      bf16x8 b1 = *(const bf16x8*)&Bs[(wn + 16 + ln) * 64 + slot];
      acc00 = __builtin_amdgcn_mfma_f32_16x16x32_bf16(a0, b0, acc00, 0, 0, 0);
      acc01 = __builtin_amdgcn_mfma_f32_16x16x32_bf16(a0, b1, acc01, 0, 0, 0);
      acc10 = __builtin_amdgcn_mfma_f32_16x16x32_bf16(a1, b0, acc10, 0, 0, 0);
      acc11 = __builtin_amdgcn_mfma_f32_16x16x32_bf16(a1, b1, acc11, 0, 0, 0);
    }
    __syncthreads();
  }

  f32x4 accs[2][2] = {{acc00, acc01}, {acc10, acc11}};
#pragma unroll
  for (int i = 0; i < 2; ++i)
#pragma unroll
    for (int j = 0; j < 2; ++j)
#pragma unroll
      for (int r = 0; r < 4; ++r) {
        int m = bm0 + wm + i * 16 + q * 4 + r;
        int n = bn0 + wn + j * 16 + ln;
        float v = accs[i][j][r];
        if (MODE == 1) {
          float o = fmaxf(v * sc[n] + sh[n], 0.0f);
          outb[(size_t)m * ldo + n] = (m < validM) ? f2bf(o) : (unsigned short)0;
        } else {
          outf[(size_t)m * ldo + n] = v + sh[n];
        }
      }
}

// =================== softmax + output scatter ===============================
__global__ void head(const float* __restrict__ fc3, float* __restrict__ out) {
  int r = blockIdx.x;
  int t = threadIdx.x;  // 0..63
  const float* row = fc3 + (size_t)r * N3P;
  float v0 = (t < NCLS) ? row[t] : -INFINITY;
  float v1 = (t + 64 < NCLS) ? row[t + 64] : -INFINITY;
  float m = fmaxf(v0, v1);
#pragma unroll
  for (int o = 32; o > 0; o >>= 1) m = fmaxf(m, __shfl_xor(m, o, 64));
  float e0 = (t < NCLS) ? expf(v0 - m) : 0.0f;
  float e1 = (t + 64 < NCLS) ? expf(v1 - m) : 0.0f;
  float s = e0 + e1;
#pragma unroll
  for (int o = 32; o > 0; o >>= 1) s += __shfl_xor(s, o, 64);
  float invs = 1.0f / s;
  float* ol = out + (size_t)r * NCLS;
  float* op = out + 162000 + (size_t)r * NCLS;
  float* ob = out + 324000 + (size_t)r * NBOX;
  if (t < NCLS) { ol[t] = v0; op[t] = e0 * invs; }
  if (t + 64 < NCLS) { ol[t + 64] = v1; op[t + 64] = e1 * invs; }
  for (int j = t; j < NBOX; j += 64) ob[j] = row[NCLS + j];
}

extern "C" void kernel_launch(void* const* d_in, const int* in_sizes, int n_in,
                              void* d_out, int out_size, void* d_ws, size_t ws_size,
                              hipStream_t stream) {
  const float* p2  = (const float*)d_in[0];
  const float* p3  = (const float*)d_in[1];
  const float* p4  = (const float*)d_in[2];
  const float* p5  = (const float*)d_in[3];
  const float* roi = (const float*)d_in[4];
  const float* c1w = (const float*)d_in[5];
  const float* c1b = (const float*)d_in[6];
  const float* g1  = (const float*)d_in[7];
  const float* b1  = (const float*)d_in[8];
  const float* m1  = (const float*)d_in[9];
  const float* v1  = (const float*)d_in[10];
  const float* c2w = (const float*)d_in[11];
  const float* c2b = (const float*)d_in[12];
  const float* g2  = (const float*)d_in[13];
  const float* b2  = (const float*)d_in[14];
  const float* m2  = (const float*)d_in[15];
  const float* v2  = (const float*)d_in[16];
  const float* lw  = (const float*)d_in[17];
  const float* lb  = (const float*)d_in[18];
  const float* bw  = (const float*)d_in[19];
  const float* bb  = (const float*)d_in[20];
  float* out = (float*)d_out;

  char* ws = (char*)d_ws;
  size_t off = 0;
  auto alloc = [&](size_t bytes) {
    void* p = ws + off;
    off = (off + bytes + 255) & ~(size_t)255;
    return p;
  };
  unsigned short* pooled = (unsigned short*)alloc((size_t)MPAD * KP * 2);
  unsigned short* w1p    = (unsigned short*)alloc((size_t)N1 * KP * 2);
  unsigned short* w2b    = (unsigned short*)alloc((size_t)N1 * N1 * 2);
  unsigned short* w3b    = (unsigned short*)alloc((size_t)N3P * N1 * 2);
  unsigned short* a2     = (unsigned short*)alloc((size_t)MPAD * N1 * 2);
  unsigned short* shd    = (unsigned short*)alloc((size_t)MPAD * N1 * 2);
  float* fc3 = (float*)alloc((size_t)MPAD * N3P * 4);
  // union region: transposed maps (44.6 MB) live only until roi_align2;
  // split-K partials (64 MB) written after — alias them.
  char* ub = (char*)alloc((size_t)KSPLIT * MPAD * N1 * 4);  // 64 MB
  unsigned short* f2t = (unsigned short*)ub;
  unsigned short* f3t = (unsigned short*)(ub + 33554432);
  unsigned short* f4t = (unsigned short*)(ub + 33554432 + 8388608);
  unsigned short* f5t = (unsigned short*)(ub + 33554432 + 8388608 + 2097152);
  float* part = (float*)ub;
  float* s1  = (float*)alloc(1024 * 4);
  float* t1  = (float*)alloc(1024 * 4);
  float* s2  = (float*)alloc(1024 * 4);
  float* t2  = (float*)alloc(1024 * 4);
  float* b3  = (float*)alloc(N3P * 4);

  prep_all<<<5569, 256, 0, stream>>>(c1w, c2w, lw, bw,
                                     c1b, g1, b1, m1, v1, c2b, g2, b2, m2, v2,
                                     lb, bb, w1p, w2b, w3b, s1, t1, s2, t2, b3);

  transpose_all<<<1360, 256, 0, stream>>>(p2, p3, p4, p5, f2t, f3t, f4t, f5t);

  roi_align2<<<MPAD, 256, 0, stream>>>(f2t, f3t, f4t, f5t, roi, pooled);

  // GEMM1: [2048 x 12544] x [1024 x 12544]^T split-K=8, XCD-swizzled
  gemm1_sk<<<1024, 256, 0, stream>>>(pooled, w1p, part);
  reduce_sk<<<MPAD, 256, 0, stream>>>(part, s1, t1, a2);

  // GEMM2: [2048 x 1024] x [1024 x 1024]^T -> BN2+ReLU -> shd (bf16)
  gemm_bt<1><<<dim3(N1 / 64, MPAD / 64), 256, 0, stream>>>(
      a2, w2b, MPAD, N1, N1, s2, t2, shd, nullptr, NROI, N1);
  // GEMM3: [2048 x 1024] x [448 x 1024]^T + bias -> fc3 (f32)
  gemm_bt<2><<<dim3(N3P / 64, MPAD / 64), 256, 0, stream>>>(
      shd, w3b, MPAD, N3P, N1, nullptr, b3, nullptr, fc3, NROI, N3P);

  head<<<NROI, 64, 0, stream>>>(fc3, out);
}

// Round 7
// 330.731 us; speedup vs baseline: 1.2210x; 1.0669x over previous
//
#include <hip/hip_runtime.h>
#include <stdint.h>

#define NROI 2000
#define MPAD 2048
#define KP   12544   // 256*49
#define N1   1024
#define NCLS 81
#define NBOX 324
#define N3   405
#define N3P  448
#define BN_EPS 0.001f
#define KSPLIT 8

typedef __attribute__((ext_vector_type(8))) short bf16x8;
typedef __attribute__((ext_vector_type(4))) float f32x4;

__device__ inline unsigned short f2bf(float f) {
  union { float f; unsigned u; } v; v.f = f;
  unsigned r = v.u + 0x7fffu + ((v.u >> 16) & 1u);
  return (unsigned short)(r >> 16);
}

__device__ inline float bf2f(unsigned short h) {
  union { unsigned u; float f; } v; v.u = (unsigned)h << 16; return v.f;
}

__device__ inline void gld16(const unsigned short* g, unsigned short* l) {
  __builtin_amdgcn_global_load_lds(
      (const __attribute__((address_space(1))) void*)g,
      (__attribute__((address_space(3))) void*)l, 16, 0, 0);
}

// K-slice table: 4 slices of 1536 + 4 of 1600 (all BK=64, no tail)
__device__ __forceinline__ void kslice(int kz, int& off, int& len) {
  if (kz < 4) { off = kz * 1536; len = 1536; }
  else        { off = 6144 + (kz - 4) * 1600; len = 1600; }
}

// =================== front: param prep + fmap transpose (merged) ===========
// blocks [0,1024): repack conv1_w -> w1p [o][hw*256+c] bf16
// blocks [1024,5120): cvt conv2_w -> bf16
// blocks [5120,5568): pack logits_w+bbox_w -> w3b (448 rows)
// block 5568: BN folding + bias concat
// blocks [5569, 6929): fmap transpose [256][HW] f32 -> [HW][256] bf16
__global__ __launch_bounds__(256) void front(
    const float* __restrict__ c1w, const float* __restrict__ c2w,
    const float* __restrict__ lw, const float* __restrict__ bw,
    const float* c1b, const float* g1, const float* b1, const float* m1, const float* v1,
    const float* c2b, const float* g2, const float* b2, const float* m2, const float* v2,
    const float* lb, const float* bb,
    const float* __restrict__ p2, const float* __restrict__ p3,
    const float* __restrict__ p4, const float* __restrict__ p5,
    unsigned short* __restrict__ w1p, unsigned short* __restrict__ w2b,
    unsigned short* __restrict__ w3b,
    unsigned short* __restrict__ f2t, unsigned short* __restrict__ f3t,
    unsigned short* __restrict__ f4t, unsigned short* __restrict__ f5t,
    float* s1, float* t1, float* s2, float* t2, float* b3) {
  __shared__ char smem_raw[64 * 260 * 2];  // 33280 B, aliased per branch
  int b = blockIdx.x;
  int t = threadIdx.x;
  if (b < 1024) {
    // repack_w1: [o][c][hw] -> [o][hw*256+c]
    unsigned short* s = (unsigned short*)smem_raw;  // KP shorts = 25088 B
    const float* src = c1w + (size_t)b * KP;
    for (int j = t; j < KP; j += 256) s[j] = f2bf(src[j]);  // s[c*49+hw]
    __syncthreads();
    unsigned short* dst = w1p + (size_t)b * KP;
    int lane = t & 63, w = t >> 6;
    int c4 = lane * 4;
    for (int j = w; j < 49; j += 4) {
      ushort4 o;
      o.x = s[(c4 + 0) * 49 + j];
      o.y = s[(c4 + 1) * 49 + j];
      o.z = s[(c4 + 2) * 49 + j];
      o.w = s[(c4 + 3) * 49 + j];
      *(ushort4*)(dst + j * 256 + c4) = o;
    }
  } else if (b < 5120) {
    int j = (b - 1024) * 256 + t;
    w2b[j] = f2bf(c2w[j]);
  } else if (b < 5568) {
    int row = b - 5120;
    for (int k = t; k < 1024; k += 256) {
      float v = (row < NCLS) ? lw[row * 1024 + k]
                             : (row < N3 ? bw[(row - NCLS) * 1024 + k] : 0.0f);
      w3b[row * 1024 + k] = f2bf(v);
    }
  } else if (b == 5568) {
    for (int i = t; i < 1024; i += 256) {
      float sc = g1[i] * rsqrtf(v1[i] + BN_EPS);
      s1[i] = sc;
      t1[i] = (c1b[i] - m1[i]) * sc + b1[i];
      float ss = g2[i] * rsqrtf(v2[i] + BN_EPS);
      s2[i] = ss;
      t2[i] = (c2b[i] - m2[i]) * ss + b2[i];
    }
    for (int i = t; i < N3P; i += 256)
      b3[i] = (i < NCLS) ? lb[i] : (i < N3 ? bb[i - NCLS] : 0.0f);
  } else {
    // fmap transpose, 64-pixel tiles
    typedef unsigned short lds_t[64][260];
    lds_t& s = *(lds_t*)smem_raw;
    int bb2 = b - 5569;
    const float* src;
    unsigned short* dst;
    int HW;
    if (bb2 < 1024)      { src = p2; dst = f2t; HW = 65536; }
    else if (bb2 < 1280) { bb2 -= 1024; src = p3; dst = f3t; HW = 16384; }
    else if (bb2 < 1344) { bb2 -= 1280; src = p4; dst = f4t; HW = 4096; }
    else                 { bb2 -= 1344; src = p5; dst = f5t; HW = 1024; }
    int p0 = bb2 * 64;
    int lane = t & 63, w = t >> 6;
    int px0 = (lane & 15) * 4;
#pragma unroll 4
    for (int it = 0; it < 16; ++it) {
      int c = w * 64 + it * 4 + (lane >> 4);
      float4 v = *(const float4*)(src + (size_t)c * HW + p0 + px0);
      s[px0 + 0][c] = f2bf(v.x);
      s[px0 + 1][c] = f2bf(v.y);
      s[px0 + 2][c] = f2bf(v.z);
      s[px0 + 3][c] = f2bf(v.w);
    }
    __syncthreads();
    int c4 = lane * 4;
#pragma unroll 4
    for (int i = 0; i < 16; ++i) {
      int p = w * 16 + i;
      ushort4 o = *(const ushort4*)&s[p][c4];
      *(ushort4*)(dst + (size_t)(p0 + p) * 256 + c4) = o;
    }
  }
}

// =================== ROI Align: gather from [HW][256] bf16 maps ============
__global__ __launch_bounds__(256) void roi_align2(
    const unsigned short* __restrict__ f2t, const unsigned short* __restrict__ f3t,
    const unsigned short* __restrict__ f4t, const unsigned short* __restrict__ f5t,
    const float* __restrict__ rois, unsigned short* __restrict__ pooled) {
  int n = blockIdx.x;
  int t = threadIdx.x;
  int lane = t & 63, w = t >> 6;
  int c0 = lane * 4;
  unsigned short* out = pooled + (size_t)n * KP;
  if (n >= NROI) {
    for (int p = w; p < 49; p += 4)
      *(ushort4*)(out + p * 256 + c0) = make_ushort4(0, 0, 0, 0);
    return;
  }
  float x1 = rois[n * 4 + 0], y1 = rois[n * 4 + 1];
  float x2 = rois[n * 4 + 2], y2 = rois[n * 4 + 3];
  float area = (y2 - y1) * (x2 - x1);
  float lvl_f = rintf(log2f(sqrtf(area) / 224.0f)) + 4.0f;
  lvl_f = fminf(fmaxf(lvl_f, 2.0f), 5.0f);
  int lvl = (int)lvl_f;
  const unsigned short* f;
  int H;
  if (lvl == 2)      { f = f2t; H = 256; }
  else if (lvl == 3) { f = f3t; H = 128; }
  else if (lvl == 4) { f = f4t; H = 64;  }
  else               { f = f5t; H = 32;  }
  int W = H;
  const float inv = 1.0f / 1024.0f;
  float yn1 = y1 * inv, xn1 = x1 * inv, yn2 = y2 * inv, xn2 = x2 * inv;
  float hs = (yn2 - yn1) * (H - 1);
  float ws = (xn2 - xn1) * (W - 1);
  float yb = yn1 * (H - 1);
  float xb = xn1 * (W - 1);

  for (int p = w; p < 49; p += 4) {
    int py = p / 7, px = p - py * 7;
    float ysv = yb + ((float)py / 6.0f) * hs;
    float xsv = xb + ((float)px / 6.0f) * ws;
    float y0f = floorf(ysv), x0f = floorf(xsv);
    float ly = ysv - y0f, lx = xsv - x0f;
    int y0 = min(max((int)y0f, 0), H - 1);
    int y1i = min(y0 + 1, H - 1);
    int x0 = min(max((int)x0f, 0), W - 1);
    int x1i = min(x0 + 1, W - 1);
    ushort4 v00 = *(const ushort4*)(f + ((size_t)y0 * W + x0) * 256 + c0);
    ushort4 v01 = *(const ushort4*)(f + ((size_t)y0 * W + x1i) * 256 + c0);
    ushort4 v10 = *(const ushort4*)(f + ((size_t)y1i * W + x0) * 256 + c0);
    ushort4 v11 = *(const ushort4*)(f + ((size_t)y1i * W + x1i) * 256 + c0);
    ushort4 o;
    {
      float a = bf2f(v00.x), bq = bf2f(v01.x), cq = bf2f(v10.x), d = bf2f(v11.x);
      float top = a + lx * (bq - a), bot = cq + lx * (d - cq);
      o.x = f2bf(top + ly * (bot - top));
    }
    {
      float a = bf2f(v00.y), bq = bf2f(v01.y), cq = bf2f(v10.y), d = bf2f(v11.y);
      float top = a + lx * (bq - a), bot = cq + lx * (d - cq);
      o.y = f2bf(top + ly * (bot - top));
    }
    {
      float a = bf2f(v00.z), bq = bf2f(v01.z), cq = bf2f(v10.z), d = bf2f(v11.z);
      float top = a + lx * (bq - a), bot = cq + lx * (d - cq);
      o.z = f2bf(top + ly * (bot - top));
    }
    {
      float a = bf2f(v00.w), bq = bf2f(v01.w), cq = bf2f(v10.w), d = bf2f(v11.w);
      float top = a + lx * (bq - a), bot = cq + lx * (d - cq);
      o.w = f2bf(top + ly * (bot - top));
    }
    *(ushort4*)(out + p * 256 + c0) = o;
  }
}

// =================== GEMM1 split-K: 128x128, BK=64, XCD + LDS-XOR swizzle ==
// Uneven K-slices (1536/1600), all BK=64 — no tail. bf16 partials out.
__global__ __launch_bounds__(256) void gemm1_sk(
    const unsigned short* __restrict__ A, const unsigned short* __restrict__ B,
    unsigned short* __restrict__ part) {
  __shared__ unsigned short As[128 * 64];  // 16 KB
  __shared__ unsigned short Bs[128 * 64];
  int bid = blockIdx.x;
  int kz = bid & 7;
  int u = bid >> 3;
  int bn0 = (u & 7) * 128;
  int bm0 = (u >> 3) * 128;
  int koff, klen;
  kslice(kz, koff, klen);
  int t = threadIdx.x;
  int lane = t & 63, w = t >> 6;
  int wm = (w & 1) * 64, wn = (w >> 1) * 64;
  int ln = lane & 15, q = lane >> 4;

  int r8 = t >> 3, j8 = t & 7;
  int sj = j8 ^ (r8 & 7);  // XOR source swizzle
  const unsigned short* ga = A + (size_t)(bm0 + r8) * KP + koff + sj * 8;
  const unsigned short* gb = B + (size_t)(bn0 + r8) * KP + koff + sj * 8;
  unsigned short* la = &As[t * 8];
  unsigned short* lb = &Bs[t * 8];
  int e = ln & 7;

  f32x4 acc[4][4] = {};

  for (int k0 = 0; k0 < klen; k0 += 64) {
#pragma unroll
    for (int i = 0; i < 4; ++i) {
      gld16(ga + k0 + (size_t)(i * 32) * KP, la + i * 2048);
      gld16(gb + k0 + (size_t)(i * 32) * KP, lb + i * 2048);
    }
    __syncthreads();
#pragma unroll
    for (int h = 0; h < 2; ++h) {
      int slot = ((h * 4 + q) ^ e) * 8;
      bf16x8 af[4], bfr[4];
#pragma unroll
      for (int i = 0; i < 4; ++i) {
        af[i]  = *(const bf16x8*)&As[(wm + i * 16 + ln) * 64 + slot];
        bfr[i] = *(const bf16x8*)&Bs[(wn + i * 16 + ln) * 64 + slot];
      }
#pragma unroll
      for (int i = 0; i < 4; ++i)
#pragma unroll
        for (int j = 0; j < 4; ++j)
          acc[i][j] = __builtin_amdgcn_mfma_f32_16x16x32_bf16(af[i], bfr[j], acc[i][j], 0, 0, 0);
    }
    __syncthreads();
  }

  unsigned short* po = part + (size_t)kz * MPAD * N1;
#pragma unroll
  for (int i = 0; i < 4; ++i)
#pragma unroll
    for (int j = 0; j < 4; ++j)
#pragma unroll
      for (int r = 0; r < 4; ++r) {
        int m = bm0 + wm + i * 16 + q * 4 + r;
        int n = bn0 + wn + j * 16 + ln;
        po[(size_t)m * N1 + n] = f2bf(acc[i][j][r]);
      }
}

// =================== split-K reduce (bf16 partials) + BN1 + ReLU ===========
__global__ void reduce_sk(const unsigned short* __restrict__ part,
                          const float* __restrict__ sc, const float* __restrict__ sh,
                          unsigned short* __restrict__ outb) {
  const size_t P = (size_t)MPAD * N1;
  int m = blockIdx.x;
  int t = threadIdx.x;
  float4 v = {0.f, 0.f, 0.f, 0.f};
#pragma unroll
  for (int kz = 0; kz < KSPLIT; ++kz) {
    ushort4 u = *(const ushort4*)(part + kz * P + (size_t)m * N1 + t * 4);
    v.x += bf2f(u.x); v.y += bf2f(u.y); v.z += bf2f(u.z); v.w += bf2f(u.w);
  }
  int n0 = t * 4;
  ushort4 o;
  if (m < NROI) {
    o.x = f2bf(fmaxf(v.x * sc[n0 + 0] + sh[n0 + 0], 0.0f));
    o.y = f2bf(fmaxf(v.y * sc[n0 + 1] + sh[n0 + 1], 0.0f));
    o.z = f2bf(fmaxf(v.z * sc[n0 + 2] + sh[n0 + 2], 0.0f));
    o.w = f2bf(fmaxf(v.w * sc[n0 + 3] + sh[n0 + 3], 0.0f));
  } else {
    o = make_ushort4(0, 0, 0, 0);
  }
  *(ushort4*)(outb + (size_t)m * N1 + n0) = o;
}

// =================== bf16 MFMA GEMM (64x64 tile, BK=64, swizzled) ==========
template <int MODE>
__global__ __launch_bounds__(256) void gemm_bt(
    const unsigned short* __restrict__ A, const unsigned short* __restrict__ B,
    int M, int N, int K,
    const float* __restrict__ sc, const float* __restrict__ sh,
    unsigned short* __restrict__ outb, float* __restrict__ outf,
    int validM, int ldo) {
  __shared__ unsigned short As[64 * 64];  // 8 KB
  __shared__ unsigned short Bs[64 * 64];
  int bm0 = blockIdx.y * 64;
  int bn0 = blockIdx.x * 64;
  int t = threadIdx.x;
  int lane = t & 63, w = t >> 6;
  int wm = (w & 1) * 32, wn = (w >> 1) * 32;
  int ln = lane & 15, q = lane >> 4;

  int r8 = t >> 3, j8 = t & 7;
  int sj = j8 ^ (r8 & 7);
  const unsigned short* ga = A + (size_t)(bm0 + r8) * K + sj * 8;
  const unsigned short* gb = B + (size_t)(bn0 + r8) * K + sj * 8;
  unsigned short* la = &As[t * 8];
  unsigned short* lb = &Bs[t * 8];
  int e = ln & 7;

  f32x4 acc00 = {0.f, 0.f, 0.f, 0.f}, acc01 = {0.f, 0.f, 0.f, 0.f};
  f32x4 acc10 = {0.f, 0.f, 0.f, 0.f}, acc11 = {0.f, 0.f, 0.f, 0.f};

  for (int k0 = 0; k0 < K; k0 += 64) {
    gld16(ga + k0, la);
    gld16(ga + k0 + (size_t)32 * K, la + 2048);
    gld16(gb + k0, lb);
    gld16(gb + k0 + (size_t)32 * K, lb + 2048);
    __syncthreads();
#pragma unroll
    for (int h = 0; h < 2; ++h) {
      int slot = ((h * 4 + q) ^ e) * 8;
      bf16x8 a0 = *(const bf16x8*)&As[(wm + ln) * 64 + slot];
      bf16x8 a1 = *(const bf16x8*)&As[(wm + 16 + ln) * 64 + slot];
      bf16x8 b0 = *(const bf16x8*)&Bs[(wn + ln) * 64 + slot];
      bf16x8 b1 = *(const bf16x8*)&Bs[(wn + 16 + ln) * 64 + slot];
      acc00 = __builtin_amdgcn_mfma_f32_16x16x32_bf16(a0, b0, acc00, 0, 0, 0);
      acc01 = __builtin_amdgcn_mfma_f32_16x16x32_bf16(a0, b1, acc01, 0, 0, 0);
      acc10 = __builtin_amdgcn_mfma_f32_16x16x32_bf16(a1, b0, acc10, 0, 0, 0);
      acc11 = __builtin_amdgcn_mfma_f32_16x16x32_bf16(a1, b1, acc11, 0, 0, 0);
    }
    __syncthreads();
  }

  f32x4 accs[2][2] = {{acc00, acc01}, {acc10, acc11}};
#pragma unroll
  for (int i = 0; i < 2; ++i)
#pragma unroll
    for (int j = 0; j < 2; ++j)
#pragma unroll
      for (int r = 0; r < 4; ++r) {
        int m = bm0 + wm + i * 16 + q * 4 + r;
        int n = bn0 + wn + j * 16 + ln;
        float v = accs[i][j][r];
        if (MODE == 1) {
          float o = fmaxf(v * sc[n] + sh[n], 0.0f);
          outb[(size_t)m * ldo + n] = (m < validM) ? f2bf(o) : (unsigned short)0;
        } else {
          outf[(size_t)m * ldo + n] = v + sh[n];
        }
      }
}

// =================== softmax + output scatter ===============================
__global__ void head(const float* __restrict__ fc3, float* __restrict__ out) {
  int r = blockIdx.x;
  int t = threadIdx.x;  // 0..63
  const float* row = fc3 + (size_t)r * N3P;
  float v0 = (t < NCLS) ? row[t] : -INFINITY;
  float v1 = (t + 64 < NCLS) ? row[t + 64] : -INFINITY;
  float m = fmaxf(v0, v1);
#pragma unroll
  for (int o = 32; o > 0; o >>= 1) m = fmaxf(m, __shfl_xor(m, o, 64));
  float e0 = (t < NCLS) ? expf(v0 - m) : 0.0f;
  float e1 = (t + 64 < NCLS) ? expf(v1 - m) : 0.0f;
  float s = e0 + e1;
#pragma unroll
  for (int o = 32; o > 0; o >>= 1) s += __shfl_xor(s, o, 64);
  float invs = 1.0f / s;
  float* ol = out + (size_t)r * NCLS;
  float* op = out + 162000 + (size_t)r * NCLS;
  float* ob = out + 324000 + (size_t)r * NBOX;
  if (t < NCLS) { ol[t] = v0; op[t] = e0 * invs; }
  if (t + 64 < NCLS) { ol[t + 64] = v1; op[t + 64] = e1 * invs; }
  for (int j = t; j < NBOX; j += 64) ob[j] = row[NCLS + j];
}

extern "C" void kernel_launch(void* const* d_in, const int* in_sizes, int n_in,
                              void* d_out, int out_size, void* d_ws, size_t ws_size,
                              hipStream_t stream) {
  const float* p2  = (const float*)d_in[0];
  const float* p3  = (const float*)d_in[1];
  const float* p4  = (const float*)d_in[2];
  const float* p5  = (const float*)d_in[3];
  const float* roi = (const float*)d_in[4];
  const float* c1w = (const float*)d_in[5];
  const float* c1b = (const float*)d_in[6];
  const float* g1  = (const float*)d_in[7];
  const float* b1  = (const float*)d_in[8];
  const float* m1  = (const float*)d_in[9];
  const float* v1  = (const float*)d_in[10];
  const float* c2w = (const float*)d_in[11];
  const float* c2b = (const float*)d_in[12];
  const float* g2  = (const float*)d_in[13];
  const float* b2  = (const float*)d_in[14];
  const float* m2  = (const float*)d_in[15];
  const float* v2  = (const float*)d_in[16];
  const float* lw  = (const float*)d_in[17];
  const float* lb  = (const float*)d_in[18];
  const float* bw  = (const float*)d_in[19];
  const float* bb  = (const float*)d_in[20];
  float* out = (float*)d_out;

  char* ws = (char*)d_ws;
  size_t off = 0;
  auto alloc = [&](size_t bytes) {
    void* p = ws + off;
    off = (off + bytes + 255) & ~(size_t)255;
    return p;
  };
  unsigned short* pooled = (unsigned short*)alloc((size_t)MPAD * KP * 2);
  unsigned short* w1p    = (unsigned short*)alloc((size_t)N1 * KP * 2);
  unsigned short* w2b    = (unsigned short*)alloc((size_t)N1 * N1 * 2);
  unsigned short* w3b    = (unsigned short*)alloc((size_t)N3P * N1 * 2);
  unsigned short* a2     = (unsigned short*)alloc((size_t)MPAD * N1 * 2);
  unsigned short* shd    = (unsigned short*)alloc((size_t)MPAD * N1 * 2);
  float* fc3 = (float*)alloc((size_t)MPAD * N3P * 4);
  // union region: transposed maps (44.6 MB) live only until roi_align2;
  // bf16 split-K partials (32 MB) written after — alias them.
  char* ub = (char*)alloc((size_t)48 * 1024 * 1024);
  unsigned short* f2t = (unsigned short*)ub;
  unsigned short* f3t = (unsigned short*)(ub + 33554432);
  unsigned short* f4t = (unsigned short*)(ub + 33554432 + 8388608);
  unsigned short* f5t = (unsigned short*)(ub + 33554432 + 8388608 + 2097152);
  unsigned short* part = (unsigned short*)ub;
  float* s1  = (float*)alloc(1024 * 4);
  float* t1  = (float*)alloc(1024 * 4);
  float* s2  = (float*)alloc(1024 * 4);
  float* t2  = (float*)alloc(1024 * 4);
  float* b3  = (float*)alloc(N3P * 4);

  front<<<6929, 256, 0, stream>>>(c1w, c2w, lw, bw,
                                  c1b, g1, b1, m1, v1, c2b, g2, b2, m2, v2,
                                  lb, bb, p2, p3, p4, p5,
                                  w1p, w2b, w3b, f2t, f3t, f4t, f5t,
                                  s1, t1, s2, t2, b3);

  roi_align2<<<MPAD, 256, 0, stream>>>(f2t, f3t, f4t, f5t, roi, pooled);

  // GEMM1: [2048 x 12544] x [1024 x 12544]^T split-K=8, XCD-swizzled
  gemm1_sk<<<1024, 256, 0, stream>>>(pooled, w1p, part);
  reduce_sk<<<MPAD, 256, 0, stream>>>(part, s1, t1, a2);

  // GEMM2: [2048 x 1024] x [1024 x 1024]^T -> BN2+ReLU -> shd (bf16)
  gemm_bt<1><<<dim3(N1 / 64, MPAD / 64), 256, 0, stream>>>(
      a2, w2b, MPAD, N1, N1, s2, t2, shd, nullptr, NROI, N1);
  // GEMM3: [2048 x 1024] x [448 x 1024]^T + bias -> fc3 (f32)
  gemm_bt<2><<<dim3(N3P / 64, MPAD / 64), 256, 0, stream>>>(
      shd, w3b, MPAD, N3P, N1, nullptr, b3, nullptr, fc3, NROI, N3P);

  head<<<NROI, 64, 0, stream>>>(fc3, out);
}